// Round 3
// baseline (3245.827 us; speedup 1.0000x reference)
//
#include <hip/hip_runtime.h>
#include <hip/hip_bf16.h>

typedef __bf16 bf16;
typedef __bf16 bf16x8 __attribute__((ext_vector_type(8)));
typedef float  f32x4  __attribute__((ext_vector_type(4)));

static __device__ __forceinline__ float b2f(bf16 x) { return (float)x; }
static __device__ __forceinline__ bf16  f2b(float x) { return (bf16)x; }
static __device__ __forceinline__ float ldval(float v) { return v; }
static __device__ __forceinline__ float ldval(bf16 v)  { return (float)v; }

// ---------------------------------------------------------------------------
// dtype detection: true-bf16 N(0,1) data never has exponent field >= 0xE0;
// f32 data read as bf16 half-words has ~12.5% of low halves there. flag=1 -> f32.
// ---------------------------------------------------------------------------
__global__ void detect_dtype(const unsigned short* __restrict__ p, int* __restrict__ flag)
{
    if (threadIdx.x == 0 && blockIdx.x == 0) {
        int big = 0;
        for (int i = 0; i < 512; ++i) {
            int e = (p[i] >> 7) & 0xFF;
            if (e >= 0xE0) big++;
        }
        *flag = (big > 0) ? 1 : 0;
    }
}

// grid-stride conversion of one tensor to canonical bf16
__global__ __launch_bounds__(256) void convert_bf16(
    const void* __restrict__ src, bf16* __restrict__ dst, int n,
    const int* __restrict__ flag)
{
    int f = *flag;
    for (int i = blockIdx.x * 256 + threadIdx.x; i < n; i += gridDim.x * 256) {
        float v = f ? ((const float*)src)[i] : (float)((const bf16*)src)[i];
        dst[i] = f2b(v);
    }
}

struct VecPack { const void* src[14]; int n[14]; };
// one block per small vector; dst slot stride 4096 elements
__global__ __launch_bounds__(256) void convert_vecs(
    VecPack vp, bf16* __restrict__ dst, const int* __restrict__ flag)
{
    int v = blockIdx.x;
    int f = *flag;
    const void* s = vp.src[v];
    int n = vp.n[v];
    bf16* d = dst + (size_t)v * 4096;
    for (int i = threadIdx.x; i < n; i += 256) {
        float x = f ? ((const float*)s)[i] : (float)((const bf16*)s)[i];
        d[i] = f2b(x);
    }
}

// ---------------------------------------------------------------------------
// GEMM: C[M,N] = A[M,K] @ B[K,N], with B supplied TRANSPOSED: Bt[n][k] (ld=ldb).
// 128x128 tile, BK=64, 256 threads = 4 waves, each wave a 64x64 quadrant of
// 4x4 mfma_f32_16x16x32_bf16 tiles. M,N % 128 == 0, K % 64 == 0 (guaranteed).
// EPI: 0 = f32 store (+bias)   1 = bf16 store of v*scale
//      2 = bf16 gelu(v+bias)   3 = f32 store (v+bias+resid)  [final output]
// ---------------------------------------------------------------------------
template <int EPI>
__global__ __launch_bounds__(256) void gemm_bt(
    const bf16* __restrict__ A0, int lda, int zsA,
    const bf16* __restrict__ B0, int ldb, int zsB,
    void* __restrict__ C0, int ldc, int zsC,
    const bf16* __restrict__ bias, const bf16* __restrict__ resid,
    float scale, int K)
{
    __shared__ __align__(16) bf16 As[128][72];   // 72*2=144B row stride (16B-aligned)
    __shared__ __align__(16) bf16 Bs[128][72];
    const int z = blockIdx.z;
    const bf16* A  = A0 + (size_t)z * zsA;
    const bf16* Bt = B0 + (size_t)z * zsB;
    const int tid  = threadIdx.x;
    const int lane = tid & 63, wave = tid >> 6;
    const int quad = lane >> 4, l16 = lane & 15;
    const size_t tm = (size_t)blockIdx.y * 128, tn = (size_t)blockIdx.x * 128;
    const int wm = (wave >> 1) * 64, wn = (wave & 1) * 64;

    f32x4 acc[4][4];
    const f32x4 zro = {0.f, 0.f, 0.f, 0.f};
    #pragma unroll
    for (int i = 0; i < 4; ++i)
        #pragma unroll
        for (int j = 0; j < 4; ++j) acc[i][j] = zro;

    for (int k0 = 0; k0 < K; k0 += 64) {
        #pragma unroll
        for (int it = 0; it < 4; ++it) {
            int cid = tid + 256 * it;          // 1024 16B-chunks per operand tile
            int r = cid >> 3, c8 = (cid & 7) << 3;
            *(uint4*)(void*)&As[r][c8] =
                *(const uint4*)(const void*)(A + (tm + r) * (size_t)lda + k0 + c8);
            *(uint4*)(void*)&Bs[r][c8] =
                *(const uint4*)(const void*)(Bt + (tn + r) * (size_t)ldb + k0 + c8);
        }
        __syncthreads();
        #pragma unroll
        for (int kk = 0; kk < 2; ++kk) {
            bf16x8 af[4], bfr[4];
            #pragma unroll
            for (int i = 0; i < 4; ++i)
                af[i] = *(const bf16x8*)(const void*)&As[wm + i*16 + l16][kk*32 + quad*8];
            #pragma unroll
            for (int j = 0; j < 4; ++j)
                bfr[j] = *(const bf16x8*)(const void*)&Bs[wn + j*16 + l16][kk*32 + quad*8];
            #pragma unroll
            for (int i = 0; i < 4; ++i)
                #pragma unroll
                for (int j = 0; j < 4; ++j)
                    acc[i][j] = __builtin_amdgcn_mfma_f32_16x16x32_bf16(
                        af[i], bfr[j], acc[i][j], 0, 0, 0);
        }
        __syncthreads();
    }

    float* Cf = (float*)C0;
    bf16*  Cb = (bf16*)C0;
    #pragma unroll
    for (int i = 0; i < 4; ++i) {
        #pragma unroll
        for (int j = 0; j < 4; ++j) {
            size_t col = tn + wn + j*16 + l16;
            float bb = bias ? b2f(bias[col]) : 0.f;
            #pragma unroll
            for (int r = 0; r < 4; ++r) {
                size_t row = tm + wm + i*16 + quad*4 + r;  // C: col=lane&15, row=quad*4+reg
                float v = acc[i][j][r] + bb;
                size_t off = (size_t)z * zsC + row * (size_t)ldc + col;
                if (EPI == 0) {
                    Cf[off] = v;
                } else if (EPI == 1) {
                    Cb[off] = f2b(v * scale);
                } else if (EPI == 2) {
                    float g = 0.5f * v * (1.f + tanhf(0.7978845608028654f *
                                  (v + 0.044715f * v * v * v)));
                    Cb[off] = f2b(g);
                } else {
                    Cf[off] = v + b2f(resid[row * (size_t)ldc + col]);
                }
            }
        }
    }
}

// ---------------------------------------------------------------------------
// bf16 transpose (canonical bf16 input): out[c*ldo + off + r] = in[r*C + c]
// ---------------------------------------------------------------------------
__global__ void transpose_b16(const unsigned short* __restrict__ in, int R, int C,
                              unsigned short* __restrict__ out, int ldo, int off)
{
    __shared__ unsigned short t[32][33];
    int c0 = blockIdx.x * 32, r0 = blockIdx.y * 32;
    int tx = threadIdx.x, ty = threadIdx.y;
    for (int i = ty; i < 32; i += 8)
        t[i][tx] = in[(size_t)(r0 + i) * C + c0 + tx];
    __syncthreads();
    for (int i = ty; i < 32; i += 8)
        out[(size_t)(c0 + i) * ldo + off + r0 + tx] = t[tx][i];
}

// dtype-branching transpose for raw weight inputs -> bf16 transposed
__global__ void transpose_any(const void* __restrict__ in, int R, int C,
                              unsigned short* __restrict__ out, int ldo,
                              const int* __restrict__ flag)
{
    __shared__ unsigned short t[32][33];
    int f = *flag;
    int c0 = blockIdx.x * 32, r0 = blockIdx.y * 32;
    int tx = threadIdx.x, ty = threadIdx.y;
    for (int i = ty; i < 32; i += 8) {
        size_t idx = (size_t)(r0 + i) * C + c0 + tx;
        bf16 v = f ? f2b(((const float*)in)[idx]) : ((const bf16*)in)[idx];
        t[i][tx] = *(unsigned short*)&v;
    }
    __syncthreads();
    for (int i = ty; i < 32; i += 8)
        out[(size_t)(c0 + i) * ldo + r0 + tx] = t[tx][i];
}

// ---------------------------------------------------------------------------
// Row LayerNorm: one block (256 thr) per row.
// ---------------------------------------------------------------------------
template <typename Tin>
__global__ __launch_bounds__(256) void ln_rows(
    const Tin* __restrict__ in, int C,
    const bf16* __restrict__ g, const bf16* __restrict__ b,
    bf16* __restrict__ out, float eps)
{
    const int row = blockIdx.x, tid = threadIdx.x;
    const Tin* p = in + (size_t)row * C;
    float s = 0.f, ss = 0.f;
    for (int c = tid; c < C; c += 256) {
        float v = ldval(p[c]);
        s += v; ss += v * v;
    }
    #pragma unroll
    for (int d = 32; d > 0; d >>= 1) { s += __shfl_xor(s, d); ss += __shfl_xor(ss, d); }
    __shared__ float red[2][4];
    int wave = tid >> 6, lane = tid & 63;
    if (lane == 0) { red[0][wave] = s; red[1][wave] = ss; }
    __syncthreads();
    s  = red[0][0] + red[0][1] + red[0][2] + red[0][3];
    ss = red[1][0] + red[1][1] + red[1][2] + red[1][3];
    float mu   = s / C;
    float var  = ss / C - mu * mu;
    float rstd = rsqrtf(var + eps);
    bf16* q = out + (size_t)row * C;
    for (int c = tid; c < C; c += 256) {
        float v = ldval(p[c]);
        q[c] = f2b((v - mu) * rstd * b2f(g[c]) + b2f(b[c]));
    }
}

// ---------------------------------------------------------------------------
// Rotary: qrot = rope(text)*DIM^-0.5 ; krotPad[b][512+t] = rope(audio_t).
// theta = t * 10000^(-c/512), pairs (c, c+512). Accurate sincosf.
// ---------------------------------------------------------------------------
__global__ __launch_bounds__(256) void rotary_kernel(
    const bf16* __restrict__ text, const bf16* __restrict__ audioT,
    bf16* __restrict__ qrot, bf16* __restrict__ krotPad)
{
    int row = blockIdx.x;              // b*2048 + t
    int t = row & 2047, b = row >> 11;
    int tid = threadIdx.x;
    const float lg = 9.210340371976184f / 512.f;   // ln(10000)/512
    size_t base = (size_t)row * 1024;
    size_t kb = ((size_t)(b * 2560 + 512 + t)) * 1024;
    for (int c = tid; c < 512; c += 256) {
        float invf = __expf(-(float)c * lg);
        float th = (float)t * invf;
        float sn, cs;
        sincosf(th, &sn, &cs);
        float q1 = b2f(text[base + c]), q2 = b2f(text[base + c + 512]);
        qrot[base + c]       = f2b((q1 * cs - q2 * sn) * 0.03125f);
        qrot[base + c + 512] = f2b((q2 * cs + q1 * sn) * 0.03125f);
        float k1 = b2f(audioT[base + c]), k2 = b2f(audioT[base + c + 512]);
        krotPad[kb + c]       = f2b(k1 * cs - k2 * sn);
        krotPad[kb + c + 512] = f2b(k2 * cs + k1 * sn);
    }
}

// ---------------------------------------------------------------------------
// Local-attention masked softmax. sim [b][w][512][1024] f32 -> attn bf16.
// valid j: (w>0 || j>=512) && (j <= 512+i).
// ---------------------------------------------------------------------------
__global__ __launch_bounds__(256) void softmax_local(
    const float* __restrict__ sim, bf16* __restrict__ attn)
{
    int i  = blockIdx.x;        // query-in-window
    int zz = blockIdx.y;        // b*4 + w
    int w  = zz & 3;
    int tid = threadIdx.x;
    const float* p = sim + ((size_t)zz * 512 + i) * 1024;
    bf16* q = attn + ((size_t)zz * 512 + i) * 1024;
    int jlo = (w == 0) ? 512 : 0;
    int jhi = 512 + i;
    float m = -1e30f;
    #pragma unroll
    for (int k = 0; k < 4; ++k) {
        int c = tid + k * 256;
        if (c >= jlo && c <= jhi) m = fmaxf(m, p[c]);
    }
    #pragma unroll
    for (int d = 32; d > 0; d >>= 1) m = fmaxf(m, __shfl_xor(m, d));
    __shared__ float red[2][4];
    int wave = tid >> 6, lane = tid & 63;
    if (lane == 0) red[0][wave] = m;
    __syncthreads();
    m = fmaxf(fmaxf(red[0][0], red[0][1]), fmaxf(red[0][2], red[0][3]));
    float pv[4];
    float s = 0.f;
    #pragma unroll
    for (int k = 0; k < 4; ++k) {
        int c = tid + k * 256;
        float e = (c >= jlo && c <= jhi) ? __expf(p[c] - m) : 0.f;
        pv[k] = e; s += e;
    }
    #pragma unroll
    for (int d = 32; d > 0; d >>= 1) s += __shfl_xor(s, d);
    if (lane == 0) red[1][wave] = s;
    __syncthreads();
    s = red[1][0] + red[1][1] + red[1][2] + red[1][3];
    float inv = 1.f / s;
    #pragma unroll
    for (int k = 0; k < 4; ++k) q[tid + k * 256] = f2b(pv[k] * inv);
}

// ---------------------------------------------------------------------------
// In-place per-(token,head) RMSNorm of q (cols 0..511) / k (cols 512..1023)
// in qkv f32 [4096][1536]. One wave per 64-elem group.
// ---------------------------------------------------------------------------
__global__ __launch_bounds__(256) void rmsnorm_qk(
    float* __restrict__ qkv,
    const bf16* __restrict__ qn_g, const bf16* __restrict__ kn_g)
{
    int gid  = blockIdx.x * 4 + (threadIdx.x >> 6);
    int lane = threadIdx.x & 63;
    int token = gid >> 4, r = gid & 15, part = r >> 3, h = r & 7;
    float* p = qkv + (size_t)token * 1536 + part * 512 + h * 64 + lane;
    float v = *p;
    float ss = v * v;
    #pragma unroll
    for (int d = 32; d > 0; d >>= 1) ss += __shfl_xor(ss, d);
    float sc = rsqrtf(ss * (1.f / 64.f) + 1e-6f);
    const bf16* gw = part ? kn_g : qn_g;
    *p = v * sc * b2f(gw[lane]);
}

// ---------------------------------------------------------------------------
// Full causal attention, DHEAD=64: one wave per (b,h,t) query, lane = dim.
// ---------------------------------------------------------------------------
__global__ __launch_bounds__(256) void flash_attn(
    const float* __restrict__ qkv, bf16* __restrict__ o)
{
    int gid  = blockIdx.x * 4 + (threadIdx.x >> 6);
    int lane = threadIdx.x & 63;
    int t = gid & 2047, h = (gid >> 11) & 7, b = gid >> 14;
    const float* qp = qkv + ((size_t)(b * 2048 + t)) * 1536 + h * 64;
    float q = qp[lane];
    const float* kb = qkv + ((size_t)(b * 2048)) * 1536 + 512 + h * 64 + lane;
    float m = -1e30f, l = 0.f, oa = 0.f;
    for (int j = 0; j <= t; ++j) {
        const float* kr = kb + (size_t)j * 1536;
        float kv = kr[0];
        float vv = kr[512];
        float s = q * kv;
        #pragma unroll
        for (int d = 32; d > 0; d >>= 1) s += __shfl_xor(s, d);
        s *= 0.125f;                      // DHEAD^-0.5
        float mn   = fmaxf(m, s);
        float corr = __expf(m - mn);
        float pe   = __expf(s - mn);
        l  = l * corr + pe;
        oa = oa * corr + pe * vv;
        m = mn;
    }
    o[((size_t)(b * 2048 + t)) * 512 + h * 64 + lane] = f2b(oa / l);
}

// ---------------------------------------------------------------------------
static void launch_gemm(int epi, hipStream_t s,
                        const bf16* A, int lda, int zsA,
                        const bf16* Bt, int ldb, int zsB,
                        void* C, int ldc, int zsC,
                        const bf16* bias, const bf16* resid, float scale,
                        int M, int N, int K, int nz)
{
    dim3 g(N / 128, M / 128, nz), blk(256);
    switch (epi) {
    case 0: gemm_bt<0><<<g, blk, 0, s>>>(A, lda, zsA, Bt, ldb, zsB, C, ldc, zsC, bias, resid, scale, K); break;
    case 1: gemm_bt<1><<<g, blk, 0, s>>>(A, lda, zsA, Bt, ldb, zsB, C, ldc, zsC, bias, resid, scale, K); break;
    case 2: gemm_bt<2><<<g, blk, 0, s>>>(A, lda, zsA, Bt, ldb, zsB, C, ldc, zsC, bias, resid, scale, K); break;
    default: gemm_bt<3><<<g, blk, 0, s>>>(A, lda, zsA, Bt, ldb, zsB, C, ldc, zsC, bias, resid, scale, K); break;
    }
}

extern "C" void kernel_launch(void* const* d_in, const int* in_sizes, int n_in,
                              void* d_out, int out_size, void* d_ws, size_t ws_size,
                              hipStream_t stream)
{
    const void* text  = d_in[0];
    const void* audio = d_in[1];
    const void* video = d_in[2];
    const void* Wa    = d_in[3];
    const void* ba    = d_in[4];
    const void* lna_g = d_in[5];
    const void* lna_b = d_in[6];
    const void* Wvid  = d_in[7];
    const void* bvid  = d_in[8];
    const void* lnv_g = d_in[9];
    const void* lnv_b = d_in[10];
    const void* ln1_g = d_in[11];
    const void* ln1_b = d_in[12];
    const void* Wq    = d_in[13];
    const void* Wkv   = d_in[14];
    const void* qn_g  = d_in[15];
    const void* kn_g  = d_in[16];
    const void* Wo    = d_in[17];
    const void* W1    = d_in[18];
    const void* b1    = d_in[19];
    const void* ln2_g = d_in[20];
    const void* ln2_b = d_in[21];
    const void* W2    = d_in[22];
    const void* b2    = d_in[23];

    char* ws = (char*)d_ws;
    size_t off = 0;
    auto alloc = [&](size_t bytes) -> char* {
        char* p = ws + off;
        off += (bytes + 255) & ~(size_t)255;
        return p;
    };
    const size_t MB = 1024 * 1024;
    int*  flag  = (int*)alloc(256);
    bf16* vecs  = (bf16*)alloc(14 * 4096 * 2);
    bf16* WqkvT = (bf16*)alloc((size_t)1536 * 1024 * 2);
    bf16* WoT   = (bf16*)alloc((size_t)1024 * 512 * 2);
    bf16* W1T   = (bf16*)alloc((size_t)4096 * 1024 * 2);
    bf16* W2T   = (bf16*)alloc((size_t)1024 * 4096 * 2);
    char* regionIn = alloc(24 * MB);   // textC,audioC,videoC -> later qkvF f32
    char* region2  = alloc(32 * MB);   // tmpF,xF f32 -> later g bf16
    char* regionH  = alloc(8 * MB);    // audioT -> h
    char* regionX  = alloc(8 * MB);    // videoT -> x2
    char* regionO  = alloc(4 * MB);    // WaT,WvT -> o
    bf16* qrot    = (bf16*)alloc((size_t)4096 * 1024 * 2);
    bf16* krotPad = (bf16*)alloc((size_t)2 * 2560 * 1024 * 2);
    bf16* VTpad   = (bf16*)alloc((size_t)2 * 1024 * 2560 * 2);
    bf16* attn    = (bf16*)alloc((size_t)8 * 512 * 1024 * 2);

    bf16*  textC  = (bf16*)regionIn;
    bf16*  audioC = textC + (size_t)4096 * 1024;
    bf16*  videoC = textC + (size_t)2 * 4096 * 1024;
    float* qkvF   = (float*)regionIn;
    float* tmpF   = (float*)region2;
    float* xF     = (float*)(region2 + 16 * MB);
    bf16*  g      = (bf16*)region2;
    bf16*  audioT = (bf16*)regionH;
    bf16*  h      = (bf16*)regionH;
    bf16*  videoT = (bf16*)regionX;
    bf16*  x2     = (bf16*)regionX;
    bf16*  WaT    = (bf16*)regionO;
    bf16*  WvT    = WaT + (size_t)1024 * 1024;
    bf16*  o      = (bf16*)regionO;

    // vec slots (stride 4096 elements)
    bf16* baC   = vecs + 0 * 4096;
    bf16* bvidC = vecs + 1 * 4096;
    bf16* lnagC = vecs + 2 * 4096;
    bf16* lnabC = vecs + 3 * 4096;
    bf16* lnvgC = vecs + 4 * 4096;
    bf16* lnvbC = vecs + 5 * 4096;
    bf16* ln1gC = vecs + 6 * 4096;
    bf16* ln1bC = vecs + 7 * 4096;
    bf16* qngC  = vecs + 8 * 4096;
    bf16* kngC  = vecs + 9 * 4096;
    bf16* b1C   = vecs + 10 * 4096;
    bf16* ln2gC = vecs + 11 * 4096;
    bf16* ln2bC = vecs + 12 * 4096;
    bf16* b2C   = vecs + 13 * 4096;

    // 1) dtype flag
    detect_dtype<<<1, 64, 0, stream>>>((const unsigned short*)text, flag);

    // 2) canonicalize big activations + small vectors
    const int NTOK = 4096 * 1024;
    convert_bf16<<<2048, 256, 0, stream>>>(text, textC, NTOK, flag);
    convert_bf16<<<2048, 256, 0, stream>>>(audio, audioC, NTOK, flag);
    convert_bf16<<<2048, 256, 0, stream>>>(video, videoC, NTOK, flag);
    VecPack vp;
    const void* vsrc[14] = {ba, bvid, lna_g, lna_b, lnv_g, lnv_b, ln1_g, ln1_b,
                            qn_g, kn_g, b1, ln2_g, ln2_b, b2};
    int vn[14] = {1024, 1024, 1024, 1024, 1024, 1024, 1024, 1024,
                  64, 64, 4096, 4096, 4096, 1024};
    for (int i = 0; i < 14; ++i) { vp.src[i] = vsrc[i]; vp.n[i] = vn[i]; }
    convert_vecs<<<14, 256, 0, stream>>>(vp, vecs, flag);

    // 3) weight transposes (dtype-branching): out[n][k] = W[k][n]
    dim3 tb(32, 8);
    transpose_any<<<dim3(32, 32), tb, 0, stream>>>(Wa, 1024, 1024, (unsigned short*)WaT, 1024, flag);
    transpose_any<<<dim3(32, 32), tb, 0, stream>>>(Wvid, 1024, 1024, (unsigned short*)WvT, 1024, flag);
    transpose_any<<<dim3(16, 32), tb, 0, stream>>>(Wq, 1024, 512, (unsigned short*)WqkvT, 1024, flag);
    transpose_any<<<dim3(32, 32), tb, 0, stream>>>(Wkv, 1024, 1024, (unsigned short*)(WqkvT + (size_t)512 * 1024), 1024, flag);
    transpose_any<<<dim3(32, 16), tb, 0, stream>>>(Wo, 512, 1024, (unsigned short*)WoT, 512, flag);
    transpose_any<<<dim3(128, 32), tb, 0, stream>>>(W1, 1024, 4096, (unsigned short*)W1T, 1024, flag);
    transpose_any<<<dim3(32, 128), tb, 0, stream>>>(W2, 4096, 1024, (unsigned short*)W2T, 4096, flag);

    // 4) adapters
    launch_gemm(0, stream, audioC, 1024, 0, WaT, 1024, 0, tmpF, 1024, 0, baC, nullptr, 1.f, 4096, 1024, 1024, 1);
    ln_rows<float><<<4096, 256, 0, stream>>>(tmpF, 1024, lnagC, lnabC, audioT, 1e-5f);
    launch_gemm(0, stream, videoC, 1024, 0, WvT, 1024, 0, tmpF, 1024, 0, bvidC, nullptr, 1.f, 4096, 1024, 1024, 1);
    ln_rows<float><<<4096, 256, 0, stream>>>(tmpF, 1024, lnvgC, lnvbC, videoT, 1e-5f);

    // 5) zero look-backward pads, rotary, padded-V transpose
    hipMemsetAsync(krotPad, 0, (size_t)2 * 2560 * 1024 * 2, stream);
    hipMemsetAsync(VTpad, 0, (size_t)2 * 1024 * 2560 * 2, stream);
    rotary_kernel<<<4096, 256, 0, stream>>>(textC, audioT, qrot, krotPad);
    for (int b = 0; b < 2; ++b)
        transpose_b16<<<dim3(32, 64), tb, 0, stream>>>(
            (const unsigned short*)(videoT + (size_t)b * 2048 * 1024), 2048, 1024,
            (unsigned short*)(VTpad + (size_t)b * 1024 * 2560), 2560, 512);

    // 6) local attention: sim -> softmax -> @V
    for (int b = 0; b < 2; ++b)
        launch_gemm(0, stream,
                    qrot + (size_t)b * 2048 * 1024, 1024, 512 * 1024,
                    krotPad + (size_t)b * 2560 * 1024, 1024, 512 * 1024,
                    tmpF + (size_t)b * 4 * 512 * 1024, 1024, 512 * 1024,
                    nullptr, nullptr, 1.f, 512, 1024, 1024, 4);
    softmax_local<<<dim3(512, 8), 256, 0, stream>>>(tmpF, attn);
    for (int b = 0; b < 2; ++b)
        launch_gemm(0, stream,
                    attn + (size_t)b * 4 * 512 * 1024, 1024, 512 * 1024,
                    VTpad + (size_t)b * 1024 * 2560, 2560, 512,
                    xF + (size_t)b * 2048 * 1024, 1024, 512 * 1024,
                    nullptr, nullptr, 1.f, 512, 1024, 1024, 4);

    // 7) ln1 -> qkv -> rmsnorm -> flash
    ln_rows<float><<<4096, 256, 0, stream>>>(xF, 1024, ln1gC, ln1bC, h, 1e-5f);
    launch_gemm(0, stream, h, 1024, 0, WqkvT, 1024, 0, qkvF, 1536, 0, nullptr, nullptr, 1.f, 4096, 1536, 1024, 1);
    rmsnorm_qk<<<16384, 256, 0, stream>>>(qkvF, qngC, kngC);
    flash_attn<<<8192, 256, 0, stream>>>(qkvF, o);

    // 8) x2 = 2*(o@Wo) ; g = gelu(x2@W1+b1) ; ln2 ; out(f32) = g@W2 + b2 + x2
    launch_gemm(1, stream, o, 512, 0, WoT, 512, 0, x2, 1024, 0, nullptr, nullptr, 2.f, 4096, 1024, 512, 1);
    launch_gemm(2, stream, x2, 1024, 0, W1T, 1024, 0, g, 4096, 0, b1C, nullptr, 1.f, 4096, 4096, 1024, 1);
    ln_rows<bf16><<<4096, 256, 0, stream>>>(g, 4096, ln2gC, ln2bC, g, 1e-5f);
    launch_gemm(3, stream, g, 4096, 0, W2T, 4096, 0, d_out, 1024, 0, b2C, x2, 1.f, 4096, 1024, 4096, 1);

    (void)in_sizes; (void)n_in; (void)out_size; (void)ws_size;
}

// Round 4
// 700.757 us; speedup vs baseline: 4.6319x; 4.6319x over previous
//
#include <hip/hip_runtime.h>
#include <hip/hip_bf16.h>

typedef __bf16 bf16;
typedef __bf16 bf16x8 __attribute__((ext_vector_type(8)));
typedef float  f32x4  __attribute__((ext_vector_type(4)));

static __device__ __forceinline__ float b2f(bf16 x) { return (float)x; }
static __device__ __forceinline__ bf16  f2b(float x) { return (bf16)x; }
static __device__ __forceinline__ float ldval(float v) { return v; }
static __device__ __forceinline__ float ldval(bf16 v)  { return (float)v; }

// ---------------------------------------------------------------------------
// dtype detection: true-bf16 N(0,1) data never has exponent field >= 0xE0;
// f32 data read as bf16 half-words has ~12.5% of low halves there. flag=1 -> f32.
// ---------------------------------------------------------------------------
__global__ void detect_dtype(const unsigned short* __restrict__ p, int* __restrict__ flag)
{
    if (threadIdx.x == 0 && blockIdx.x == 0) {
        int big = 0;
        for (int i = 0; i < 512; ++i) {
            int e = (p[i] >> 7) & 0xFF;
            if (e >= 0xE0) big++;
        }
        *flag = (big > 0) ? 1 : 0;
    }
}

// grid-stride conversion of one tensor to canonical bf16
__global__ __launch_bounds__(256) void convert_bf16(
    const void* __restrict__ src, bf16* __restrict__ dst, int n,
    const int* __restrict__ flag)
{
    int f = *flag;
    for (int i = blockIdx.x * 256 + threadIdx.x; i < n; i += gridDim.x * 256) {
        float v = f ? ((const float*)src)[i] : (float)((const bf16*)src)[i];
        dst[i] = f2b(v);
    }
}

struct VecPack { const void* src[14]; int n[14]; };
// one block per small vector; dst slot stride 4096 elements
__global__ __launch_bounds__(256) void convert_vecs(
    VecPack vp, bf16* __restrict__ dst, const int* __restrict__ flag)
{
    int v = blockIdx.x;
    int f = *flag;
    const void* s = vp.src[v];
    int n = vp.n[v];
    bf16* d = dst + (size_t)v * 4096;
    for (int i = threadIdx.x; i < n; i += 256) {
        float x = f ? ((const float*)s)[i] : (float)((const bf16*)s)[i];
        d[i] = f2b(x);
    }
}

// ---------------------------------------------------------------------------
// GEMM: C[M,N] = A[M,K] @ B[K,N], with B supplied TRANSPOSED: Bt[n][k] (ld=ldb).
// 128x128 tile, BK=64, 256 threads = 4 waves, each wave a 64x64 quadrant of
// 4x4 mfma_f32_16x16x32_bf16 tiles.
// EPI: 0 = f32 store (+bias)   1 = bf16 store of v*scale
//      2 = bf16 gelu(v+bias)   3 = f32 store (v+bias+resid)  [final output]
// ---------------------------------------------------------------------------
template <int EPI>
__global__ __launch_bounds__(256) void gemm_bt(
    const bf16* __restrict__ A0, int lda, int zsA,
    const bf16* __restrict__ B0, int ldb, int zsB,
    void* __restrict__ C0, int ldc, int zsC,
    const bf16* __restrict__ bias, const bf16* __restrict__ resid,
    float scale, int K)
{
    __shared__ __align__(16) bf16 As[128][72];
    __shared__ __align__(16) bf16 Bs[128][72];
    const int z = blockIdx.z;
    const bf16* A  = A0 + (size_t)z * zsA;
    const bf16* Bt = B0 + (size_t)z * zsB;
    const int tid  = threadIdx.x;
    const int lane = tid & 63, wave = tid >> 6;
    const int quad = lane >> 4, l16 = lane & 15;
    const size_t tm = (size_t)blockIdx.y * 128, tn = (size_t)blockIdx.x * 128;
    const int wm = (wave >> 1) * 64, wn = (wave & 1) * 64;

    f32x4 acc[4][4];
    const f32x4 zro = {0.f, 0.f, 0.f, 0.f};
    #pragma unroll
    for (int i = 0; i < 4; ++i)
        #pragma unroll
        for (int j = 0; j < 4; ++j) acc[i][j] = zro;

    for (int k0 = 0; k0 < K; k0 += 64) {
        #pragma unroll
        for (int it = 0; it < 4; ++it) {
            int cid = tid + 256 * it;
            int r = cid >> 3, c8 = (cid & 7) << 3;
            *(uint4*)(void*)&As[r][c8] =
                *(const uint4*)(const void*)(A + (tm + r) * (size_t)lda + k0 + c8);
            *(uint4*)(void*)&Bs[r][c8] =
                *(const uint4*)(const void*)(Bt + (tn + r) * (size_t)ldb + k0 + c8);
        }
        __syncthreads();
        #pragma unroll
        for (int kk = 0; kk < 2; ++kk) {
            bf16x8 af[4], bfr[4];
            #pragma unroll
            for (int i = 0; i < 4; ++i)
                af[i] = *(const bf16x8*)(const void*)&As[wm + i*16 + l16][kk*32 + quad*8];
            #pragma unroll
            for (int j = 0; j < 4; ++j)
                bfr[j] = *(const bf16x8*)(const void*)&Bs[wn + j*16 + l16][kk*32 + quad*8];
            #pragma unroll
            for (int i = 0; i < 4; ++i)
                #pragma unroll
                for (int j = 0; j < 4; ++j)
                    acc[i][j] = __builtin_amdgcn_mfma_f32_16x16x32_bf16(
                        af[i], bfr[j], acc[i][j], 0, 0, 0);
        }
        __syncthreads();
    }

    float* Cf = (float*)C0;
    bf16*  Cb = (bf16*)C0;
    #pragma unroll
    for (int i = 0; i < 4; ++i) {
        #pragma unroll
        for (int j = 0; j < 4; ++j) {
            size_t col = tn + wn + j*16 + l16;
            float bb = bias ? b2f(bias[col]) : 0.f;
            #pragma unroll
            for (int r = 0; r < 4; ++r) {
                size_t row = tm + wm + i*16 + quad*4 + r;
                float v = acc[i][j][r] + bb;
                size_t off = (size_t)z * zsC + row * (size_t)ldc + col;
                if (EPI == 0) {
                    Cf[off] = v;
                } else if (EPI == 1) {
                    Cb[off] = f2b(v * scale);
                } else if (EPI == 2) {
                    float g = 0.5f * v * (1.f + tanhf(0.7978845608028654f *
                                  (v + 0.044715f * v * v * v)));
                    Cb[off] = f2b(g);
                } else {
                    Cf[off] = v + b2f(resid[row * (size_t)ldc + col]);
                }
            }
        }
    }
}

// ---------------------------------------------------------------------------
// bf16 transpose (canonical bf16 input): out[c*ldo + off + r] = in[r*C + c]
// ---------------------------------------------------------------------------
__global__ void transpose_b16(const unsigned short* __restrict__ in, int R, int C,
                              unsigned short* __restrict__ out, int ldo, int off)
{
    __shared__ unsigned short t[32][33];
    int c0 = blockIdx.x * 32, r0 = blockIdx.y * 32;
    int tx = threadIdx.x, ty = threadIdx.y;
    for (int i = ty; i < 32; i += 8)
        t[i][tx] = in[(size_t)(r0 + i) * C + c0 + tx];
    __syncthreads();
    for (int i = ty; i < 32; i += 8)
        out[(size_t)(c0 + i) * ldo + off + r0 + tx] = t[tx][i];
}

// dtype-branching transpose for raw weight inputs -> bf16 transposed
__global__ void transpose_any(const void* __restrict__ in, int R, int C,
                              unsigned short* __restrict__ out, int ldo,
                              const int* __restrict__ flag)
{
    __shared__ unsigned short t[32][33];
    int f = *flag;
    int c0 = blockIdx.x * 32, r0 = blockIdx.y * 32;
    int tx = threadIdx.x, ty = threadIdx.y;
    for (int i = ty; i < 32; i += 8) {
        size_t idx = (size_t)(r0 + i) * C + c0 + tx;
        bf16 v = f ? f2b(((const float*)in)[idx]) : ((const bf16*)in)[idx];
        t[i][tx] = *(unsigned short*)&v;
    }
    __syncthreads();
    for (int i = ty; i < 32; i += 8)
        out[(size_t)(c0 + i) * ldo + r0 + tx] = t[tx][i];
}

// ---------------------------------------------------------------------------
// V transpose into per-head Vt[bh][64][2048] bf16 (B-operand [n=d][k=key]).
// qkv f32 [4096][1536], v at col 1024+h*64. grid (2, 64, 16), block (32,8).
// ---------------------------------------------------------------------------
__global__ void transpose_v(const float* __restrict__ qkv, bf16* __restrict__ Vt)
{
    __shared__ float t[32][33];
    int bh = blockIdx.z, b = bh >> 3, h = bh & 7;
    const float* src = qkv + (size_t)b * 2048 * 1536 + 1024 + h * 64;
    int c0 = blockIdx.x * 32, r0 = blockIdx.y * 32;   // c: d, r: token
    int tx = threadIdx.x, ty = threadIdx.y;
    for (int i = ty; i < 32; i += 8)
        t[i][tx] = src[(size_t)(r0 + i) * 1536 + c0 + tx];
    __syncthreads();
    bf16* dst = Vt + (size_t)bh * 64 * 2048;
    for (int i = ty; i < 32; i += 8)
        dst[(size_t)(c0 + i) * 2048 + r0 + tx] = f2b(t[tx][i]);
}

// ---------------------------------------------------------------------------
// Row LayerNorm: one block (256 thr) per row.
// ---------------------------------------------------------------------------
template <typename Tin>
__global__ __launch_bounds__(256) void ln_rows(
    const Tin* __restrict__ in, int C,
    const bf16* __restrict__ g, const bf16* __restrict__ b,
    bf16* __restrict__ out, float eps)
{
    const int row = blockIdx.x, tid = threadIdx.x;
    const Tin* p = in + (size_t)row * C;
    float s = 0.f, ss = 0.f;
    for (int c = tid; c < C; c += 256) {
        float v = ldval(p[c]);
        s += v; ss += v * v;
    }
    #pragma unroll
    for (int d = 32; d > 0; d >>= 1) { s += __shfl_xor(s, d); ss += __shfl_xor(ss, d); }
    __shared__ float red[2][4];
    int wave = tid >> 6, lane = tid & 63;
    if (lane == 0) { red[0][wave] = s; red[1][wave] = ss; }
    __syncthreads();
    s  = red[0][0] + red[0][1] + red[0][2] + red[0][3];
    ss = red[1][0] + red[1][1] + red[1][2] + red[1][3];
    float mu   = s / C;
    float var  = ss / C - mu * mu;
    float rstd = rsqrtf(var + eps);
    bf16* q = out + (size_t)row * C;
    for (int c = tid; c < C; c += 256) {
        float v = ldval(p[c]);
        q[c] = f2b((v - mu) * rstd * b2f(g[c]) + b2f(b[c]));
    }
}

// ---------------------------------------------------------------------------
// Rotary: qrot = rope(text)*DIM^-0.5 ; krotPad[b][512+t] = rope(audio_t).
// ---------------------------------------------------------------------------
__global__ __launch_bounds__(256) void rotary_kernel(
    const bf16* __restrict__ text, const bf16* __restrict__ audioT,
    bf16* __restrict__ qrot, bf16* __restrict__ krotPad)
{
    int row = blockIdx.x;              // b*2048 + t
    int t = row & 2047, b = row >> 11;
    int tid = threadIdx.x;
    const float lg = 9.210340371976184f / 512.f;   // ln(10000)/512
    size_t base = (size_t)row * 1024;
    size_t kb = ((size_t)(b * 2560 + 512 + t)) * 1024;
    for (int c = tid; c < 512; c += 256) {
        float invf = __expf(-(float)c * lg);
        float th = (float)t * invf;
        float sn, cs;
        sincosf(th, &sn, &cs);
        float q1 = b2f(text[base + c]), q2 = b2f(text[base + c + 512]);
        qrot[base + c]       = f2b((q1 * cs - q2 * sn) * 0.03125f);
        qrot[base + c + 512] = f2b((q2 * cs + q1 * sn) * 0.03125f);
        float k1 = b2f(audioT[base + c]), k2 = b2f(audioT[base + c + 512]);
        krotPad[kb + c]       = f2b(k1 * cs - k2 * sn);
        krotPad[kb + c + 512] = f2b(k2 * cs + k1 * sn);
    }
}

// ---------------------------------------------------------------------------
// Local-attention masked softmax. sim [b][w][512][1024] f32 -> attn bf16.
// ---------------------------------------------------------------------------
__global__ __launch_bounds__(256) void softmax_local(
    const float* __restrict__ sim, bf16* __restrict__ attn)
{
    int i  = blockIdx.x;
    int zz = blockIdx.y;        // b*4 + w
    int w  = zz & 3;
    int tid = threadIdx.x;
    const float* p = sim + ((size_t)zz * 512 + i) * 1024;
    bf16* q = attn + ((size_t)zz * 512 + i) * 1024;
    int jlo = (w == 0) ? 512 : 0;
    int jhi = 512 + i;
    float m = -1e30f;
    #pragma unroll
    for (int k = 0; k < 4; ++k) {
        int c = tid + k * 256;
        if (c >= jlo && c <= jhi) m = fmaxf(m, p[c]);
    }
    #pragma unroll
    for (int d = 32; d > 0; d >>= 1) m = fmaxf(m, __shfl_xor(m, d));
    __shared__ float red[2][4];
    int wave = tid >> 6, lane = tid & 63;
    if (lane == 0) red[0][wave] = m;
    __syncthreads();
    m = fmaxf(fmaxf(red[0][0], red[0][1]), fmaxf(red[0][2], red[0][3]));
    float pv[4];
    float s = 0.f;
    #pragma unroll
    for (int k = 0; k < 4; ++k) {
        int c = tid + k * 256;
        float e = (c >= jlo && c <= jhi) ? __expf(p[c] - m) : 0.f;
        pv[k] = e; s += e;
    }
    #pragma unroll
    for (int d = 32; d > 0; d >>= 1) s += __shfl_xor(s, d);
    if (lane == 0) red[1][wave] = s;
    __syncthreads();
    s = red[1][0] + red[1][1] + red[1][2] + red[1][3];
    float inv = 1.f / s;
    #pragma unroll
    for (int k = 0; k < 4; ++k) q[tid + k * 256] = f2b(pv[k] * inv);
}

// ---------------------------------------------------------------------------
// pack_qk: per-(token,head) RMSNorm of q/k from qkv f32 [4096][1536], packed
// to per-head bf16 Qp/Kp[bh][2048][64]. Q gets the exact *0.125 scale folded.
// One wave per (token, part, head): gid = token*16 + part*8 + h.
// ---------------------------------------------------------------------------
__global__ __launch_bounds__(256) void pack_qk(
    const float* __restrict__ qkv, bf16* __restrict__ Qp, bf16* __restrict__ Kp,
    const bf16* __restrict__ qn_g, const bf16* __restrict__ kn_g)
{
    int gid  = blockIdx.x * 4 + (threadIdx.x >> 6);
    int lane = threadIdx.x & 63;
    int token = gid >> 4, r = gid & 15, part = r >> 3, h = r & 7;
    const float* p = qkv + (size_t)token * 1536 + part * 512 + h * 64 + lane;
    float v = *p;
    float ss = v * v;
    #pragma unroll
    for (int d = 32; d > 0; d >>= 1) ss += __shfl_xor(ss, d);
    float sc = rsqrtf(ss * (1.f / 64.f) + 1e-6f);
    const bf16* gw = part ? kn_g : qn_g;
    float outv = v * sc * b2f(gw[lane]);
    if (!part) outv *= 0.125f;                      // DHEAD^-0.5 (exact pow2)
    int b = token >> 11, t = token & 2047;
    bf16* dst = (part ? Kp : Qp) + ((size_t)(b * 8 + h) * 2048 + t) * 64 + lane;
    *dst = f2b(outv);
}

// ---------------------------------------------------------------------------
// MFMA flash attention (causal, D=64). Grid (32 q-blocks, 16 bh), 256 thr.
// Wave w owns 16 query rows qm+w*16.. ; key tiles of 64.
// Layout facts (verified): A-frag m=lane&15, k=quad*8+j; C-frag col=lane&15,
// row=quad*4+reg. P round-trips through LDS (C-layout -> A-layout).
// ---------------------------------------------------------------------------
__global__ __launch_bounds__(256) void flash_mfma(
    const bf16* __restrict__ Qp, const bf16* __restrict__ Kp,
    const bf16* __restrict__ Vt, bf16* __restrict__ o)
{
    __shared__ __align__(16) bf16 Ks[64][72];       // [key][d]
    __shared__ __align__(16) bf16 Vs[64][72];       // [d][key]
    __shared__ __align__(16) bf16 Ps[4][16][72];    // per-wave P [qrow][key]
    const int bh = blockIdx.y, b = bh >> 3, h = bh & 7;
    const int qm = (31 - (int)blockIdx.x) * 64;     // long rows first
    const int tid = threadIdx.x, wave = tid >> 6, lane = tid & 63;
    const int quad = lane >> 4, l16 = lane & 15;
    const bf16* Qg = Qp + (size_t)bh * 2048 * 64;
    const bf16* Kg = Kp + (size_t)bh * 2048 * 64;
    const bf16* Vg = Vt + (size_t)bh * 64 * 2048;

    // Q A-frags: rows qm+wave*16+l16, k = kk*32 + quad*8 + j
    const int qrow = qm + wave * 16 + l16;
    bf16x8 qa[2];
    qa[0] = *(const bf16x8*)(const void*)(Qg + (size_t)qrow * 64 + quad * 8);
    qa[1] = *(const bf16x8*)(const void*)(Qg + (size_t)qrow * 64 + 32 + quad * 8);

    f32x4 oacc[4];
    const f32x4 zro = {0.f, 0.f, 0.f, 0.f};
    #pragma unroll
    for (int j = 0; j < 4; ++j) oacc[j] = zro;
    float mst[4] = {-1e30f, -1e30f, -1e30f, -1e30f};
    float lst[4] = {0.f, 0.f, 0.f, 0.f};

    const int ldr = tid >> 2, ldc = (tid & 3) * 16;   // staging coords
    for (int jt = 0; jt <= qm; jt += 64) {
        // stage K tile [64 keys][64 d] and Vt tile [64 d][64 keys]
        *(uint4*)(void*)&Ks[ldr][ldc] =
            *(const uint4*)(const void*)(Kg + (size_t)(jt + ldr) * 64 + ldc);
        *(uint4*)(void*)&Ks[ldr][ldc + 8] =
            *(const uint4*)(const void*)(Kg + (size_t)(jt + ldr) * 64 + ldc + 8);
        *(uint4*)(void*)&Vs[ldr][ldc] =
            *(const uint4*)(const void*)(Vg + (size_t)ldr * 2048 + jt + ldc);
        *(uint4*)(void*)&Vs[ldr][ldc + 8] =
            *(const uint4*)(const void*)(Vg + (size_t)ldr * 2048 + jt + ldc + 8);
        __syncthreads();

        // S = Q.K^T : 4 j-frags (64 keys), k-dim 64
        f32x4 s[4];
        #pragma unroll
        for (int j = 0; j < 4; ++j) s[j] = zro;
        #pragma unroll
        for (int kk = 0; kk < 2; ++kk) {
            #pragma unroll
            for (int j = 0; j < 4; ++j) {
                bf16x8 kb = *(const bf16x8*)(const void*)&Ks[j*16 + l16][kk*32 + quad*8];
                s[j] = __builtin_amdgcn_mfma_f32_16x16x32_bf16(qa[kk], kb, s[j], 0, 0, 0);
            }
        }

        // causal mask (only the final tile can clip)
        if (jt + 63 > qm + wave * 16) {
            #pragma unroll
            for (int j = 0; j < 4; ++j) {
                int key = jt + j * 16 + l16;
                #pragma unroll
                for (int r = 0; r < 4; ++r) {
                    int row = qm + wave * 16 + quad * 4 + r;
                    if (key > row) s[j][r] = -1e30f;
                }
            }
        }

        // online softmax: rows live across the 16-lane group (col = l16)
        f32x4 tmax = s[0];
        #pragma unroll
        for (int j = 1; j < 4; ++j)
            #pragma unroll
            for (int r = 0; r < 4; ++r) tmax[r] = fmaxf(tmax[r], s[j][r]);
        #pragma unroll
        for (int r = 0; r < 4; ++r) {
            float tv = tmax[r];
            #pragma unroll
            for (int d = 1; d < 16; d <<= 1) tv = fmaxf(tv, __shfl_xor(tv, d));
            tmax[r] = tv;
        }
        float scl[4];
        #pragma unroll
        for (int r = 0; r < 4; ++r) {
            float mn = fmaxf(mst[r], tmax[r]);
            scl[r] = __expf(mst[r] - mn);
            mst[r] = mn;
        }
        f32x4 psum = zro;
        #pragma unroll
        for (int j = 0; j < 4; ++j)
            #pragma unroll
            for (int r = 0; r < 4; ++r) {
                float e = __expf(s[j][r] - mst[r]);
                s[j][r] = e;
                psum[r] += e;
            }
        #pragma unroll
        for (int r = 0; r < 4; ++r) {
            float tv = psum[r];
            #pragma unroll
            for (int d = 1; d < 16; d <<= 1) tv += __shfl_xor(tv, d);
            lst[r] = lst[r] * scl[r] + tv;
        }
        #pragma unroll
        for (int j = 0; j < 4; ++j)
            #pragma unroll
            for (int r = 0; r < 4; ++r) oacc[j][r] *= scl[r];

        // P: C-layout -> LDS -> A-layout
        #pragma unroll
        for (int j = 0; j < 4; ++j)
            #pragma unroll
            for (int r = 0; r < 4; ++r)
                Ps[wave][quad*4 + r][j*16 + l16] = f2b(s[j][r]);
        bf16x8 pa[2];
        pa[0] = *(const bf16x8*)(const void*)&Ps[wave][l16][quad*8];
        pa[1] = *(const bf16x8*)(const void*)&Ps[wave][l16][32 + quad*8];

        // O += P.V : 4 n-frags over d, k-dim = 64 keys
        #pragma unroll
        for (int kk = 0; kk < 2; ++kk) {
            #pragma unroll
            for (int j = 0; j < 4; ++j) {
                bf16x8 vb = *(const bf16x8*)(const void*)&Vs[j*16 + l16][kk*32 + quad*8];
                oacc[j] = __builtin_amdgcn_mfma_f32_16x16x32_bf16(pa[kk], vb, oacc[j], 0, 0, 0);
            }
        }
        __syncthreads();
    }

    // epilogue: normalize, store to o[token][h*64+d]
    #pragma unroll
    for (int j = 0; j < 4; ++j) {
        #pragma unroll
        for (int r = 0; r < 4; ++r) {
            int t = qm + wave * 16 + quad * 4 + r;
            o[((size_t)(b * 2048 + t)) * 512 + h * 64 + j * 16 + l16] =
                f2b(oacc[j][r] / lst[r]);
        }
    }
}

// ---------------------------------------------------------------------------
static void launch_gemm(int epi, hipStream_t s,
                        const bf16* A, int lda, int zsA,
                        const bf16* Bt, int ldb, int zsB,
                        void* C, int ldc, int zsC,
                        const bf16* bias, const bf16* resid, float scale,
                        int M, int N, int K, int nz)
{
    dim3 g(N / 128, M / 128, nz), blk(256);
    switch (epi) {
    case 0: gemm_bt<0><<<g, blk, 0, s>>>(A, lda, zsA, Bt, ldb, zsB, C, ldc, zsC, bias, resid, scale, K); break;
    case 1: gemm_bt<1><<<g, blk, 0, s>>>(A, lda, zsA, Bt, ldb, zsB, C, ldc, zsC, bias, resid, scale, K); break;
    case 2: gemm_bt<2><<<g, blk, 0, s>>>(A, lda, zsA, Bt, ldb, zsB, C, ldc, zsC, bias, resid, scale, K); break;
    default: gemm_bt<3><<<g, blk, 0, s>>>(A, lda, zsA, Bt, ldb, zsB, C, ldc, zsC, bias, resid, scale, K); break;
    }
}

extern "C" void kernel_launch(void* const* d_in, const int* in_sizes, int n_in,
                              void* d_out, int out_size, void* d_ws, size_t ws_size,
                              hipStream_t stream)
{
    const void* text  = d_in[0];
    const void* audio = d_in[1];
    const void* video = d_in[2];
    const void* Wa    = d_in[3];
    const void* ba    = d_in[4];
    const void* lna_g = d_in[5];
    const void* lna_b = d_in[6];
    const void* Wvid  = d_in[7];
    const void* bvid  = d_in[8];
    const void* lnv_g = d_in[9];
    const void* lnv_b = d_in[10];
    const void* ln1_g = d_in[11];
    const void* ln1_b = d_in[12];
    const void* Wq    = d_in[13];
    const void* Wkv   = d_in[14];
    const void* qn_g  = d_in[15];
    const void* kn_g  = d_in[16];
    const void* Wo    = d_in[17];
    const void* W1    = d_in[18];
    const void* b1    = d_in[19];
    const void* ln2_g = d_in[20];
    const void* ln2_b = d_in[21];
    const void* W2    = d_in[22];
    const void* b2    = d_in[23];

    char* ws = (char*)d_ws;
    size_t off = 0;
    auto alloc = [&](size_t bytes) -> char* {
        char* p = ws + off;
        off += (bytes + 255) & ~(size_t)255;
        return p;
    };
    const size_t MB = 1024 * 1024;
    int*  flag  = (int*)alloc(256);
    bf16* vecs  = (bf16*)alloc(14 * 4096 * 2);
    bf16* WqkvT = (bf16*)alloc((size_t)1536 * 1024 * 2);
    bf16* WoT   = (bf16*)alloc((size_t)1024 * 512 * 2);
    bf16* W1T   = (bf16*)alloc((size_t)4096 * 1024 * 2);
    bf16* W2T   = (bf16*)alloc((size_t)1024 * 4096 * 2);
    char* regionIn = alloc(24 * MB);   // textC,audioC,videoC -> later qkvF f32
    char* region2  = alloc(32 * MB);   // tmpF,xF f32 -> later g bf16
    char* regionH  = alloc(8 * MB);    // audioT -> h
    char* regionX  = alloc(8 * MB);    // videoT -> x2
    char* regionO  = alloc(4 * MB);    // WaT,WvT -> o
    bf16* qrot    = (bf16*)alloc((size_t)4096 * 1024 * 2);
    bf16* krotPad = (bf16*)alloc((size_t)2 * 2560 * 1024 * 2);
    bf16* VTpad   = (bf16*)alloc((size_t)2 * 1024 * 2560 * 2);
    bf16* attn    = (bf16*)alloc((size_t)8 * 512 * 1024 * 2);

    bf16*  textC  = (bf16*)regionIn;
    bf16*  audioC = textC + (size_t)4096 * 1024;
    bf16*  videoC = textC + (size_t)2 * 4096 * 1024;
    float* qkvF   = (float*)regionIn;
    float* tmpF   = (float*)region2;
    float* xF     = (float*)(region2 + 16 * MB);
    bf16*  g      = (bf16*)region2;
    bf16*  audioT = (bf16*)regionH;
    bf16*  h      = (bf16*)regionH;
    bf16*  videoT = (bf16*)regionX;
    bf16*  x2     = (bf16*)regionX;
    bf16*  WaT    = (bf16*)regionO;
    bf16*  WvT    = WaT + (size_t)1024 * 1024;
    bf16*  o      = (bf16*)regionO;
    // flash buffers alias dead local-attention regions:
    bf16*  Qp     = qrot;      // 4 MB needed, 8 MB region (dead after sim GEMM)
    bf16*  Kp     = krotPad;   // 4 MB needed, 10 MB region (dead after sim GEMM)
    bf16*  Vth    = attn;      // 4 MB needed, 8 MB region (dead after attn@V GEMM)

    // vec slots (stride 4096 elements)
    bf16* baC   = vecs + 0 * 4096;
    bf16* bvidC = vecs + 1 * 4096;
    bf16* lnagC = vecs + 2 * 4096;
    bf16* lnabC = vecs + 3 * 4096;
    bf16* lnvgC = vecs + 4 * 4096;
    bf16* lnvbC = vecs + 5 * 4096;
    bf16* ln1gC = vecs + 6 * 4096;
    bf16* ln1bC = vecs + 7 * 4096;
    bf16* qngC  = vecs + 8 * 4096;
    bf16* kngC  = vecs + 9 * 4096;
    bf16* b1C   = vecs + 10 * 4096;
    bf16* ln2gC = vecs + 11 * 4096;
    bf16* ln2bC = vecs + 12 * 4096;
    bf16* b2C   = vecs + 13 * 4096;

    // 1) dtype flag
    detect_dtype<<<1, 64, 0, stream>>>((const unsigned short*)text, flag);

    // 2) canonicalize big activations + small vectors
    const int NTOK = 4096 * 1024;
    convert_bf16<<<2048, 256, 0, stream>>>(text, textC, NTOK, flag);
    convert_bf16<<<2048, 256, 0, stream>>>(audio, audioC, NTOK, flag);
    convert_bf16<<<2048, 256, 0, stream>>>(video, videoC, NTOK, flag);
    VecPack vp;
    const void* vsrc[14] = {ba, bvid, lna_g, lna_b, lnv_g, lnv_b, ln1_g, ln1_b,
                            qn_g, kn_g, b1, ln2_g, ln2_b, b2};
    int vn[14] = {1024, 1024, 1024, 1024, 1024, 1024, 1024, 1024,
                  64, 64, 4096, 4096, 4096, 1024};
    for (int i = 0; i < 14; ++i) { vp.src[i] = vsrc[i]; vp.n[i] = vn[i]; }
    convert_vecs<<<14, 256, 0, stream>>>(vp, vecs, flag);

    // 3) weight transposes (dtype-branching): out[n][k] = W[k][n]
    dim3 tb(32, 8);
    transpose_any<<<dim3(32, 32), tb, 0, stream>>>(Wa, 1024, 1024, (unsigned short*)WaT, 1024, flag);
    transpose_any<<<dim3(32, 32), tb, 0, stream>>>(Wvid, 1024, 1024, (unsigned short*)WvT, 1024, flag);
    transpose_any<<<dim3(16, 32), tb, 0, stream>>>(Wq, 1024, 512, (unsigned short*)WqkvT, 1024, flag);
    transpose_any<<<dim3(32, 32), tb, 0, stream>>>(Wkv, 1024, 1024, (unsigned short*)(WqkvT + (size_t)512 * 1024), 1024, flag);
    transpose_any<<<dim3(32, 16), tb, 0, stream>>>(Wo, 512, 1024, (unsigned short*)WoT, 512, flag);
    transpose_any<<<dim3(128, 32), tb, 0, stream>>>(W1, 1024, 4096, (unsigned short*)W1T, 1024, flag);
    transpose_any<<<dim3(32, 128), tb, 0, stream>>>(W2, 4096, 1024, (unsigned short*)W2T, 4096, flag);

    // 4) adapters
    launch_gemm(0, stream, audioC, 1024, 0, WaT, 1024, 0, tmpF, 1024, 0, baC, nullptr, 1.f, 4096, 1024, 1024, 1);
    ln_rows<float><<<4096, 256, 0, stream>>>(tmpF, 1024, lnagC, lnabC, audioT, 1e-5f);
    launch_gemm(0, stream, videoC, 1024, 0, WvT, 1024, 0, tmpF, 1024, 0, bvidC, nullptr, 1.f, 4096, 1024, 1024, 1);
    ln_rows<float><<<4096, 256, 0, stream>>>(tmpF, 1024, lnvgC, lnvbC, videoT, 1e-5f);

    // 5) zero look-backward pads, rotary, padded-V transpose
    hipMemsetAsync(krotPad, 0, (size_t)2 * 2560 * 1024 * 2, stream);
    hipMemsetAsync(VTpad, 0, (size_t)2 * 1024 * 2560 * 2, stream);
    rotary_kernel<<<4096, 256, 0, stream>>>(textC, audioT, qrot, krotPad);
    for (int b = 0; b < 2; ++b)
        transpose_b16<<<dim3(32, 64), tb, 0, stream>>>(
            (const unsigned short*)(videoT + (size_t)b * 2048 * 1024), 2048, 1024,
            (unsigned short*)(VTpad + (size_t)b * 1024 * 2560), 2560, 512);

    // 6) local attention: sim -> softmax -> @V
    for (int b = 0; b < 2; ++b)
        launch_gemm(0, stream,
                    qrot + (size_t)b * 2048 * 1024, 1024, 512 * 1024,
                    krotPad + (size_t)b * 2560 * 1024, 1024, 512 * 1024,
                    tmpF + (size_t)b * 4 * 512 * 1024, 1024, 512 * 1024,
                    nullptr, nullptr, 1.f, 512, 1024, 1024, 4);
    softmax_local<<<dim3(512, 8), 256, 0, stream>>>(tmpF, attn);
    for (int b = 0; b < 2; ++b)
        launch_gemm(0, stream,
                    attn + (size_t)b * 4 * 512 * 1024, 1024, 512 * 1024,
                    VTpad + (size_t)b * 1024 * 2560, 2560, 512,
                    xF + (size_t)b * 2048 * 1024, 1024, 512 * 1024,
                    nullptr, nullptr, 1.f, 512, 1024, 1024, 4);

    // 7) ln1 -> qkv -> pack(rmsnorm) -> V transpose -> MFMA flash
    ln_rows<float><<<4096, 256, 0, stream>>>(xF, 1024, ln1gC, ln1bC, h, 1e-5f);
    launch_gemm(0, stream, h, 1024, 0, WqkvT, 1024, 0, qkvF, 1536, 0, nullptr, nullptr, 1.f, 4096, 1536, 1024, 1);
    pack_qk<<<16384, 256, 0, stream>>>(qkvF, Qp, Kp, qngC, kngC);
    transpose_v<<<dim3(2, 64, 16), tb, 0, stream>>>(qkvF, Vth);
    flash_mfma<<<dim3(32, 16), 256, 0, stream>>>(Qp, Kp, Vth, o);

    // 8) x2 = 2*(o@Wo) ; g = gelu(x2@W1+b1) ; ln2 ; out(f32) = g@W2 + b2 + x2
    launch_gemm(1, stream, o, 512, 0, WoT, 512, 0, x2, 1024, 0, nullptr, nullptr, 2.f, 4096, 1024, 512, 1);
    launch_gemm(2, stream, x2, 1024, 0, W1T, 1024, 0, g, 4096, 0, b1C, nullptr, 1.f, 4096, 4096, 1024, 1);
    ln_rows<bf16><<<4096, 256, 0, stream>>>(g, 4096, ln2gC, ln2bC, g, 1e-5f);
    launch_gemm(3, stream, g, 4096, 0, W2T, 4096, 0, d_out, 1024, 0, b2C, x2, 1.f, 4096, 1024, 4096, 1);

    (void)in_sizes; (void)n_in; (void)out_size; (void)ws_size;
}